// Round 3
// baseline (99.212 us; speedup 1.0000x reference)
//
#include <hip/hip_runtime.h>
#include <hip/hip_bf16.h>

#define BDIM 4096
#define DDIM 512
#define NSPLIT 64
#define CPS (BDIM / NSPLIT)      // 64 cols per split (one 64 KB LDS tile)
#define KS (DDIM / 16)           // 32 mfma k-steps (K=16 each)
#define RPW 32                   // rows per wave (A register-resident)
#define RPB 128                  // rows per block (4 waves)

typedef __bf16 bf16x8 __attribute__((ext_vector_type(8)));
typedef float f32x16 __attribute__((ext_vector_type(16)));
typedef unsigned short ushort_t;

__device__ inline ushort_t f2bf(float f) {
  __hip_bfloat16 h = __float2bfloat16(f);
  return *reinterpret_cast<ushort_t*>(&h);
}

// order-preserving float <-> uint mapping (monotonic) for atomic min/max
__device__ inline unsigned int enc_f32(float x) {
  unsigned int u = __float_as_uint(x);
  return (u & 0x80000000u) ? ~u : (u | 0x80000000u);
}
__device__ inline float dec_f32(unsigned int e) {
  unsigned int u = (e & 0x80000000u) ? (e ^ 0x80000000u) : ~e;
  return __uint_as_float(u);
}

// ---------------- kernel 1: L2-normalize rows, emit bf16; init atomics -----
__global__ __launch_bounds__(256) void norm_kernel(const float* __restrict__ x,
                                                   ushort_t* __restrict__ e,
                                                   unsigned int* __restrict__ minpos_e,
                                                   unsigned int* __restrict__ maxneg_e) {
  if (blockIdx.x == 0) {  // init atomic arrays (runs before gemm in stream order)
    const unsigned int init_min = enc_f32(1e30f);
    const unsigned int init_max = enc_f32(-1e30f);
    for (int i = threadIdx.x; i < BDIM; i += 256) {
      minpos_e[i] = init_min;
      maxneg_e[i] = init_max;
    }
  }
  const int row  = blockIdx.x * 4 + (threadIdx.x >> 6);
  const int lane = threadIdx.x & 63;
  const float4* xr = reinterpret_cast<const float4*>(x + (size_t)row * DDIM);
  float4 v0 = xr[lane];
  float4 v1 = xr[lane + 64];
  float ss = v0.x*v0.x + v0.y*v0.y + v0.z*v0.z + v0.w*v0.w
           + v1.x*v1.x + v1.y*v1.y + v1.z*v1.z + v1.w*v1.w;
#pragma unroll
  for (int off = 32; off >= 1; off >>= 1) ss += __shfl_xor(ss, off);
  const float inv = 1.0f / fmaxf(sqrtf(ss), 1e-12f);

  ushort4 p0, p1;
  p0.x = f2bf(v0.x * inv); p0.y = f2bf(v0.y * inv);
  p0.z = f2bf(v0.z * inv); p0.w = f2bf(v0.w * inv);
  p1.x = f2bf(v1.x * inv); p1.y = f2bf(v1.y * inv);
  p1.z = f2bf(v1.z * inv); p1.w = f2bf(v1.w * inv);
  ushort4* er = reinterpret_cast<ushort4*>(e + (size_t)row * DDIM);
  er[lane]      = p0;
  er[lane + 64] = p1;
}

// ------- kernel 2: fused S = E E^T tile + masked row min/max reduce -------
// Single-stage: whole 64-col split staged once (linear LDS dest via
// global_load_lds, inverse-swizzled global source, swizzled ds_read).
__global__ __launch_bounds__(256, 2) void gemm_reduce_kernel(
    const ushort_t* __restrict__ e, const int* __restrict__ labels,
    unsigned int* __restrict__ minpos_e, unsigned int* __restrict__ maxneg_e) {
  __shared__ __align__(16) char Blds[CPS * 1024];

  const int tid  = threadIdx.x;
  const int wave = tid >> 6;
  const int lane = tid & 63;
  const int c    = lane & 31;   // local col in tile; also local A-row index
  const int hi   = lane >> 5;   // 0/1
  const int swz  = (c & 7) << 4;

  const int rowbase = blockIdx.y * RPB + wave * RPW;
  const int colbase = blockIdx.x * CPS;   // x = split -> same-split blocks share XCD

  // stage 64 cols x 1 KB, swizzle folded into the global source address
  {
    const char* gsrc = (const char*)e + (size_t)colbase * (DDIM * 2);
#pragma unroll
    for (int q = 0; q < 16; ++q) {
      const int cc = wave * 16 + q;
      const int gb = cc * 1024 + ((lane * 16) ^ ((cc & 7) << 4));
      __builtin_amdgcn_global_load_lds(
          (const __attribute__((address_space(1))) void*)(gsrc + gb),
          (__attribute__((address_space(3))) void*)(&Blds[cc * 1024]),
          16, 0, 0);
    }
  }

  // A fragments -> registers: lane holds row (rowbase+c), k = ks*16 + hi*8 + [0..8)
  bf16x8 afrag[KS];
  {
    const ushort_t* aptr = e + (size_t)(rowbase + c) * DDIM + hi * 8;
#pragma unroll
    for (int ks = 0; ks < KS; ++ks)
      afrag[ks] = *reinterpret_cast<const bf16x8*>(aptr + ks * 16);
  }

  __syncthreads();  // stage + A loads complete

  f32x16 acc0 = {0.f,0.f,0.f,0.f,0.f,0.f,0.f,0.f,0.f,0.f,0.f,0.f,0.f,0.f,0.f,0.f};
  f32x16 acc1 = acc0;
  const char* bb0 = Blds + c * 1024;
  const char* bb1 = Blds + (c + 32) * 1024;
#pragma unroll
  for (int ks = 0; ks < KS; ++ks) {
    const int off = (ks * 32 + hi * 16) ^ swz;
    bf16x8 b0 = *reinterpret_cast<const bf16x8*>(bb0 + off);
    bf16x8 b1 = *reinterpret_cast<const bf16x8*>(bb1 + off);
    acc0 = __builtin_amdgcn_mfma_f32_32x32x16_bf16(afrag[ks], b0, acc0, 0, 0, 0);
    acc1 = __builtin_amdgcn_mfma_f32_32x32x16_bf16(afrag[ks], b1, acc1, 0, 0, 0);
  }

  // ----- masked min/max update (labels loaded only now: short live ranges) --
  const int lj0 = labels[colbase + c];
  const int lj1 = labels[colbase + 32 + c];
  const int j0 = colbase + c;
  const int j1 = colbase + 32 + c;

  float minpos[16], maxneg[16];
#pragma unroll
  for (int r = 0; r < 16; ++r) {
    const int i  = rowbase + (r & 3) + 8 * (r >> 2) + 4 * hi;
    const int li = labels[i];
    float mp = 1e30f, mn = -1e30f;
    const float s0 = acc0[r];
    const float s1 = acc1[r];
    if (li == lj0) { if (i != j0) mp = s0; } else { mn = s0; }
    if (li == lj1) { if (i != j1) mp = fminf(mp, s1); } else { mn = fmaxf(mn, s1); }
    minpos[r] = mp; maxneg[r] = mn;
  }

  // reduce across the 32 lanes (same hi) holding different cols of same rows
#pragma unroll
  for (int off = 1; off < 32; off <<= 1) {
#pragma unroll
    for (int r = 0; r < 16; ++r) {
      minpos[r] = fminf(minpos[r], __shfl_xor(minpos[r], off));
      maxneg[r] = fmaxf(maxneg[r], __shfl_xor(maxneg[r], off));
    }
  }
  if (c == 0) {
#pragma unroll
    for (int r = 0; r < 16; ++r) {
      const int i = rowbase + (r & 3) + 8 * (r >> 2) + 4 * hi;
      if (minpos[r] < 1e29f) atomicMin(&minpos_e[i], enc_f32(minpos[r]));
      if (maxneg[r] > -1e29f) atomicMax(&maxneg_e[i], enc_f32(maxneg[r]));
    }
  }
}

// ---------------- kernel 3: combine -> scalar loss ----------------
__global__ __launch_bounds__(1024) void finalize_kernel(
    const unsigned int* __restrict__ minpos_e, const unsigned int* __restrict__ maxneg_e,
    float* __restrict__ out) {
  const int tid = threadIdx.x;
  float sum = 0.f;
  int cnt = 0;
  for (int row = tid; row < BDIM; row += 1024) {
    const float mp = dec_f32(minpos_e[row]);
    const float mn = dec_f32(maxneg_e[row]);
    if (mp < 1e29f && mn > -1e29f) {
      // hp - hn + margin = (1-mp) - (1-mn) + 0.2 = mn - mp + 0.2
      sum += fmaxf(0.f, mn - mp + 0.2f);
      cnt += 1;
    }
  }
#pragma unroll
  for (int off = 32; off >= 1; off >>= 1) {
    sum += __shfl_xor(sum, off);
    cnt += __shfl_xor(cnt, off);
  }
  __shared__ float wsum[16];
  __shared__ int   wcnt[16];
  const int wv = tid >> 6, ln = tid & 63;
  if (ln == 0) { wsum[wv] = sum; wcnt[wv] = cnt; }
  __syncthreads();
  if (tid == 0) {
    float S = 0.f; int C = 0;
    for (int w = 0; w < 16; ++w) { S += wsum[w]; C += wcnt[w]; }
    out[0] = S / (float)(C > 0 ? C : 1);
  }
}

extern "C" void kernel_launch(void* const* d_in, const int* in_sizes, int n_in,
                              void* d_out, int out_size, void* d_ws, size_t ws_size,
                              hipStream_t stream) {
  const float* x      = (const float*)d_in[0];
  const int*   labels = (const int*)d_in[1];
  float* out = (float*)d_out;

  char* ws = (char*)d_ws;
  ushort_t* e             = (ushort_t*)ws;                           // 4 MB bf16 E
  unsigned int* minpos_e  = (unsigned int*)(ws + (size_t)BDIM * DDIM * 2);
  unsigned int* maxneg_e  = minpos_e + BDIM;

  norm_kernel<<<BDIM / 4, 256, 0, stream>>>(x, e, minpos_e, maxneg_e);
  dim3 g(NSPLIT, BDIM / RPB);   // x = split (XCD-clustered), y = row-block
  gemm_reduce_kernel<<<g, 256, 0, stream>>>(e, labels, minpos_e, maxneg_e);
  finalize_kernel<<<1, 1024, 0, stream>>>(minpos_e, maxneg_e, out);
}

// Round 4
// 36.817 us; speedup vs baseline: 2.6947x; 2.6947x over previous
//
#include <hip/hip_runtime.h>
#include <hip/hip_bf16.h>

#define BDIM 4096
#define DDIM 512
#define BT 128                    // block tile (rows == cols)
#define NKT 8                     // K tiles: 512 / 64
#define NPAN (BDIM / BT)          // 32 panels
#define GRIDX (NPAN * NPAN)       // 1024 blocks

typedef __bf16 bf16x8 __attribute__((ext_vector_type(8)));
typedef float f32x4 __attribute__((ext_vector_type(4)));
typedef unsigned short ushort_t;

__device__ inline ushort_t f2bf(float f) {
  __hip_bfloat16 h = __float2bfloat16(f);
  return *reinterpret_cast<ushort_t*>(&h);
}

// order-preserving float <-> uint mapping (monotonic) for atomic min/max
__device__ inline unsigned int enc_f32(float x) {
  unsigned int u = __float_as_uint(x);
  return (u & 0x80000000u) ? ~u : (u | 0x80000000u);
}
__device__ inline float dec_f32(unsigned int e) {
  unsigned int u = (e & 0x80000000u) ? (e ^ 0x80000000u) : ~e;
  return __uint_as_float(u);
}

// ---------------- kernel 1: L2-normalize rows, emit bf16; init atomics -----
__global__ __launch_bounds__(256) void norm_kernel(const float* __restrict__ x,
                                                   ushort_t* __restrict__ e,
                                                   unsigned int* __restrict__ minpos_e,
                                                   unsigned int* __restrict__ maxneg_e) {
  if (blockIdx.x == 0) {  // init atomic arrays (stream order: before gemm)
    const unsigned int init_min = enc_f32(1e30f);
    const unsigned int init_max = enc_f32(-1e30f);
    for (int i = threadIdx.x; i < BDIM; i += 256) {
      minpos_e[i] = init_min;
      maxneg_e[i] = init_max;
    }
  }
  const int row  = blockIdx.x * 4 + (threadIdx.x >> 6);
  const int lane = threadIdx.x & 63;
  const float4* xr = reinterpret_cast<const float4*>(x + (size_t)row * DDIM);
  float4 v0 = xr[lane];
  float4 v1 = xr[lane + 64];
  float ss = v0.x*v0.x + v0.y*v0.y + v0.z*v0.z + v0.w*v0.w
           + v1.x*v1.x + v1.y*v1.y + v1.z*v1.z + v1.w*v1.w;
#pragma unroll
  for (int off = 32; off >= 1; off >>= 1) ss += __shfl_xor(ss, off);
  const float inv = 1.0f / fmaxf(sqrtf(ss), 1e-12f);

  ushort4 p0, p1;
  p0.x = f2bf(v0.x * inv); p0.y = f2bf(v0.y * inv);
  p0.z = f2bf(v0.z * inv); p0.w = f2bf(v0.w * inv);
  p1.x = f2bf(v1.x * inv); p1.y = f2bf(v1.y * inv);
  p1.z = f2bf(v1.z * inv); p1.w = f2bf(v1.w * inv);
  ushort4* er = reinterpret_cast<ushort4*>(e + (size_t)row * DDIM);
  er[lane]      = p0;
  er[lane + 64] = p1;
}

// ------- kernel 2: m97-structure GEMM tile + fused col-direction reduce -----
// LDS per buffer: A tile [128 rows][64 k] bf16 (16 KB) + B tile same (16 KB).
// T2 swizzle (byte ^= (row&7)<<4 within each 128B row) applied on BOTH sides:
// inverse-swizzled global source (gload_lds dest stays linear) + swizzled read.
#define STAGE(buf, kt)                                                         \
  do {                                                                         \
    _Pragma("unroll")                                                          \
    for (int q = 0; q < 8; ++q) {                                              \
      const int off  = q * 4096 + tid * 16;   /* 0..32767 */                   \
      const int loff = off & 16383;                                            \
      const int row  = loff >> 7;                                              \
      const int kb   = loff & 127;                                             \
      const int pan  = (q < 4) ? Ibase : Jbase;                                \
      const char* src = (const char*)e + (size_t)(pan + row) * (DDIM * 2) +    \
                        (kt) * 128 + (kb ^ ((row & 7) << 4));                  \
      __builtin_amdgcn_global_load_lds(                                        \
          (const __attribute__((address_space(1))) void*)src,                  \
          (__attribute__((address_space(3))) void*)(&Blds[buf][off]),          \
          16, 0, 0);                                                           \
    }                                                                          \
  } while (0)

__global__ __launch_bounds__(256, 2) void gemm_reduce_kernel(
    const ushort_t* __restrict__ e, const int* __restrict__ labels,
    unsigned int* __restrict__ minpos_e, unsigned int* __restrict__ maxneg_e) {
  __shared__ __align__(16) char Blds[2][32768];
  __shared__ int Llab[256];

  const int tid  = threadIdx.x;
  const int wave = tid >> 6;
  const int lane = tid & 63;
  const int l15  = lane & 15;
  const int g    = lane >> 4;     // 0..3
  const int wr   = wave >> 1;     // 0..1 row half
  const int wc   = wave & 1;      // 0..1 col half

  // bijective XCD swizzle: 1024 blocks = 8 XCDs x 128; J fastest within XCD
  const int bid  = blockIdx.x;
  const int sbid = (bid & 7) * (GRIDX / 8) + (bid >> 3);
  const int Ibase = (sbid >> 5) * BT;
  const int Jbase = (sbid & 31) * BT;

  // stage labels for this block's rows (I) and cols (J)
  if (tid < 128) Llab[tid] = labels[Ibase + tid];
  else           Llab[tid] = labels[Jbase + tid - 128];

  f32x4 acc[4][4];
#pragma unroll
  for (int m = 0; m < 4; ++m)
#pragma unroll
    for (int n = 0; n < 4; ++n) acc[m][n] = (f32x4){0.f, 0.f, 0.f, 0.f};

  STAGE(0, 0);
  __syncthreads();  // vmcnt drained at barrier: buf0 + labels ready

  for (int kt = 0; kt < NKT; ++kt) {
    if (kt + 1 < NKT) STAGE((kt + 1) & 1, kt + 1);  // async prefetch

    const char* Ab = Blds[kt & 1];
    const char* Bb = Blds[kt & 1] + 16384;
#pragma unroll
    for (int kk = 0; kk < 2; ++kk) {
      bf16x8 a[4], b[4];
#pragma unroll
      for (int m = 0; m < 4; ++m) {
        const int row = wr * 64 + m * 16 + l15;
        a[m] = *reinterpret_cast<const bf16x8*>(
            Ab + row * 128 + ((kk * 64 + g * 16) ^ ((row & 7) << 4)));
      }
#pragma unroll
      for (int n = 0; n < 4; ++n) {
        const int row = wc * 64 + n * 16 + l15;
        b[n] = *reinterpret_cast<const bf16x8*>(
            Bb + row * 128 + ((kk * 64 + g * 16) ^ ((row & 7) << 4)));
      }
#pragma unroll
      for (int m = 0; m < 4; ++m)
#pragma unroll
        for (int n = 0; n < 4; ++n)
          acc[m][n] = __builtin_amdgcn_mfma_f32_16x16x32_bf16(a[m], b[n],
                                                              acc[m][n], 0, 0, 0);
    }
    __syncthreads();  // staged(kt+1) complete + cur buffer release
  }

  // ---- fused epilogue: per-COLUMN masked min/max (S symmetric => col==row) --
  // C/D layout 16x16: col = l15, row = g*4 + reg. A lane's 16 values (m,reg)
  // all live in column (n, l15) -> in-lane reduce + 2 shuffles across g.
  float cmp[4], cmx[4];
  int lj[4], gj[4];
#pragma unroll
  for (int n = 0; n < 4; ++n) {
    cmp[n] = 1e30f; cmx[n] = -1e30f;
    gj[n]  = Jbase + wc * 64 + n * 16 + l15;
    lj[n]  = Llab[128 + wc * 64 + n * 16 + l15];
  }
#pragma unroll
  for (int m = 0; m < 4; ++m) {
#pragma unroll
    for (int r = 0; r < 4; ++r) {
      const int rloc = wr * 64 + m * 16 + g * 4 + r;
      const int li   = Llab[rloc];
      const int gi   = Ibase + rloc;
#pragma unroll
      for (int n = 0; n < 4; ++n) {
        const float v = acc[m][n][r];
        if (li == lj[n]) {
          if (gi != gj[n]) cmp[n] = fminf(cmp[n], v);
        } else {
          cmx[n] = fmaxf(cmx[n], v);
        }
      }
    }
  }
  // reduce across the 4 lanes (g = 0..3) sharing each column
#pragma unroll
  for (int off = 16; off <= 32; off <<= 1) {
#pragma unroll
    for (int n = 0; n < 4; ++n) {
      cmp[n] = fminf(cmp[n], __shfl_xor(cmp[n], off));
      cmx[n] = fmaxf(cmx[n], __shfl_xor(cmx[n], off));
    }
  }
  if (g == 0) {
#pragma unroll
    for (int n = 0; n < 4; ++n) {
      if (cmp[n] < 1e29f)  atomicMin(&minpos_e[gj[n]], enc_f32(cmp[n]));
      if (cmx[n] > -1e29f) atomicMax(&maxneg_e[gj[n]], enc_f32(cmx[n]));
    }
  }
}

// ---------------- kernel 3: combine -> scalar loss ----------------
__global__ __launch_bounds__(1024) void finalize_kernel(
    const unsigned int* __restrict__ minpos_e, const unsigned int* __restrict__ maxneg_e,
    float* __restrict__ out) {
  const int tid = threadIdx.x;
  float sum = 0.f;
  int cnt = 0;
  for (int row = tid; row < BDIM; row += 1024) {
    const float mp = dec_f32(minpos_e[row]);
    const float mn = dec_f32(maxneg_e[row]);
    if (mp < 1e29f && mn > -1e29f) {
      // hp - hn + margin = (1-mp) - (1-mn) + 0.2 = mn - mp + 0.2
      sum += fmaxf(0.f, mn - mp + 0.2f);
      cnt += 1;
    }
  }
#pragma unroll
  for (int off = 32; off >= 1; off >>= 1) {
    sum += __shfl_xor(sum, off);
    cnt += __shfl_xor(cnt, off);
  }
  __shared__ float wsum[16];
  __shared__ int   wcnt[16];
  const int wv = tid >> 6, ln = tid & 63;
  if (ln == 0) { wsum[wv] = sum; wcnt[wv] = cnt; }
  __syncthreads();
  if (tid == 0) {
    float S = 0.f; int C = 0;
    for (int w = 0; w < 16; ++w) { S += wsum[w]; C += wcnt[w]; }
    out[0] = S / (float)(C > 0 ? C : 1);
  }
}

extern "C" void kernel_launch(void* const* d_in, const int* in_sizes, int n_in,
                              void* d_out, int out_size, void* d_ws, size_t ws_size,
                              hipStream_t stream) {
  const float* x      = (const float*)d_in[0];
  const int*   labels = (const int*)d_in[1];
  float* out = (float*)d_out;

  char* ws = (char*)d_ws;
  ushort_t* e            = (ushort_t*)ws;                            // 4 MB bf16 E
  unsigned int* minpos_e = (unsigned int*)(ws + (size_t)BDIM * DDIM * 2);
  unsigned int* maxneg_e = minpos_e + BDIM;

  norm_kernel<<<BDIM / 4, 256, 0, stream>>>(x, e, minpos_e, maxneg_e);
  gemm_reduce_kernel<<<GRIDX, 256, 0, stream>>>(e, labels, minpos_e, maxneg_e);
  finalize_kernel<<<1, 1024, 0, stream>>>(minpos_e, maxneg_e, out);
}